// Round 11
// baseline (304.886 us; speedup 1.0000x reference)
//
#include <hip/hip_runtime.h>
#include <math.h>

#define L_SEQ 32768
#define PL  16384     // u16 per LDS plane (128x128 swizzled)
#define GPL 16384     // u16 global plane stride (128x128 matrices, hi/lo)

typedef unsigned short u16;
typedef float f32x4 __attribute__((ext_vector_type(4)));
typedef short bf16x8 __attribute__((ext_vector_type(8)));
typedef u16 u16x4 __attribute__((ext_vector_type(4)));

__device__ __forceinline__ u16 f2bf(float x) {
  unsigned u = __float_as_uint(x);
  u = u + 0x7FFFu + ((u >> 16) & 1u);
  return (u16)(u >> 16);
}
__device__ __forceinline__ float bf2f(u16 h) { return __uint_as_float(((unsigned)h) << 16); }
__device__ __forceinline__ int MIDX(int r, int c) { return (r << 7) + (c ^ ((r & 7) << 3)); }
__device__ __forceinline__ f32x4 MF(bf16x8 a, bf16x8 b, f32x4 c) {
  return __builtin_amdgcn_mfma_f32_16x16x32_bf16(a, b, c, 0, 0, 0);
}
__device__ __forceinline__ void pack4(const float* v, u16x4& hi, u16x4& lo) {
#pragma unroll
  for (int j = 0; j < 4; ++j) {
    u16 h = f2bf(v[j]);
    hi[j] = h;
    lo[j] = f2bf(v[j] - bf2f(h));
  }
}
// plain (own-block) global fragment, plane stride pl
__device__ __forceinline__ void gfragP(const u16* g, int pl, int row, int kp,
                                       bf16x8& h, bf16x8& l) {
  h = *(const bf16x8*)(g + row * 128 + kp);
  l = *(const bf16x8*)(g + pl + row * 128 + kp);
}
// coherent cross-block loads/stores (agent scope -> memory-side cache)
__device__ __forceinline__ bf16x8 cohld16(const u16* p) {
  unsigned long long a = __hip_atomic_load((const unsigned long long*)p,
                                           __ATOMIC_RELAXED, __HIP_MEMORY_SCOPE_AGENT);
  unsigned long long b = __hip_atomic_load((const unsigned long long*)p + 1,
                                           __ATOMIC_RELAXED, __HIP_MEMORY_SCOPE_AGENT);
  union { unsigned long long x[2]; bf16x8 v; } u;
  u.x[0] = a; u.x[1] = b;
  return u.v;
}
__device__ __forceinline__ void gfragC(const u16* g, int row, int kp,
                                       bf16x8& h, bf16x8& l) {
  h = cohld16(g + row * 128 + kp);
  l = cohld16(g + GPL + row * 128 + kp);
}
__device__ __forceinline__ void cohst8(u16* p, u16x4 v) {
  union { u16x4 s; unsigned long long x; } u;
  u.s = v;
  __hip_atomic_store((unsigned long long*)p, u.x, __ATOMIC_RELAXED,
                     __HIP_MEMORY_SCOPE_AGENT);
}
__device__ __forceinline__ void waitflag(int* f) {
  if (threadIdx.x == 0) {
    int it = 0;
    while (__hip_atomic_load(f, __ATOMIC_ACQUIRE, __HIP_MEMORY_SCOPE_AGENT) == 0 &&
           it < (1 << 28)) {
      __builtin_amdgcn_s_sleep(8);
      ++it;
    }
  }
  __syncthreads();
}
__device__ __forceinline__ void setflag(int* f) {
  __syncthreads();  // all prior global stores drained (vmcnt0 before barrier)
  if (threadIdx.x == 0)
    __hip_atomic_store(f, 1, __ATOMIC_RELEASE, __HIP_MEMORY_SCOPE_AGENT);
}

// ---------------------------------------------------------------------------
// Producer step (1024 thr, 16 waves, 32x32 tiles): in-place LDS product
// M,Bt <- (M x Bt-cols), fp32 via 3 bf16 MFMAs; dual acc/accT maintains both
// row-major (M) and col-major (Bt) LDS copies.
// MK: 1 = A from LDS M | 2 = A from gA global rows, epilogue v=c3*(v+U12)-I
// DMP: 0 none | 1 plain rows -> gd | 2 atomic rows -> gd | 3 atomic colsT -> gd
// ERS (0/2): U12 rider rows via gAe; M2 adds T+T2+I (gT1,gT2x) -> gOe
// ---------------------------------------------------------------------------
template<int MK, int DMP, int ERS, bool M2>
__device__ void prod_step(u16* lds, const u16* gA, const u16* gU, float c3,
                          u16* gd, const u16* gAe, u16* gOe,
                          const u16* gT1, const u16* gT2x) {
  u16* Mb = lds;
  u16* Tb = lds + 2 * PL;
  const int t = threadIdx.x, lane = t & 63, la = lane & 15, g = lane >> 4;
  const int w = t >> 6, wr = w >> 2, wc = w & 3;
  const int r0 = wr << 5, c0 = wc << 5;
  constexpr int ERN = (ERS > 0) ? ERS : 1;

  __syncthreads();

  f32x4 acc[2][2], accT[2][2], accE[ERN][2];
#pragma unroll
  for (int i = 0; i < 2; ++i)
#pragma unroll
    for (int j = 0; j < 2; ++j) {
      acc[i][j] = (f32x4){0.f, 0.f, 0.f, 0.f};
      accT[i][j] = (f32x4){0.f, 0.f, 0.f, 0.f};
    }
#pragma unroll
  for (int f = 0; f < ERN; ++f)
#pragma unroll
    for (int j = 0; j < 2; ++j) accE[f][j] = (f32x4){0.f, 0.f, 0.f, 0.f};

#pragma unroll
  for (int kb = 0; kb < 4; ++kb) {
    const int kp = (kb << 5) + (g << 3);
    bf16x8 Ah[2], Al[2], Bh[2], Bl[2];
#pragma unroll
    for (int fr = 0; fr < 2; ++fr) {
      int ar = r0 + (fr << 4) + la;
      if constexpr (MK == 1) {
        Ah[fr] = *(const bf16x8*)(Mb + MIDX(ar, kp));
        Al[fr] = *(const bf16x8*)(Mb + PL + MIDX(ar, kp));
      } else {
        gfragP(gA, GPL, ar, kp, Ah[fr], Al[fr]);
      }
    }
#pragma unroll
    for (int fc = 0; fc < 2; ++fc) {
      int bc = c0 + (fc << 4) + la;
      Bh[fc] = *(const bf16x8*)(Tb + MIDX(bc, kp));
      Bl[fc] = *(const bf16x8*)(Tb + PL + MIDX(bc, kp));
    }
    bf16x8 Eh[ERN], El[ERN];
    if constexpr (ERS > 0) {
#pragma unroll
      for (int f = 0; f < ERS; ++f) {
        int er = (wr << 4) + (f << 6) + la;
        gfragP(gAe, GPL, er, kp, Eh[f], El[f]);
      }
    }
#pragma unroll
    for (int fr = 0; fr < 2; ++fr)
#pragma unroll
      for (int fc = 0; fc < 2; ++fc) {
        acc[fr][fc] = MF(Ah[fr], Bh[fc], acc[fr][fc]);
        acc[fr][fc] = MF(Ah[fr], Bl[fc], acc[fr][fc]);
        acc[fr][fc] = MF(Al[fr], Bh[fc], acc[fr][fc]);
        accT[fr][fc] = MF(Bh[fc], Ah[fr], accT[fr][fc]);
        accT[fr][fc] = MF(Bh[fc], Al[fr], accT[fr][fc]);
        accT[fr][fc] = MF(Bl[fc], Ah[fr], accT[fr][fc]);
      }
    if constexpr (ERS > 0) {
#pragma unroll
      for (int f = 0; f < ERS; ++f)
#pragma unroll
        for (int fc = 0; fc < 2; ++fc) {
          accE[f][fc] = MF(Bh[fc], Eh[f], accE[f][fc]);
          accE[f][fc] = MF(Bh[fc], El[f], accE[f][fc]);
          accE[f][fc] = MF(Bl[fc], Eh[f], accE[f][fc]);
        }
    }
  }

  __syncthreads();  // slot reads drained -> in-place LDS writes safe

#pragma unroll
  for (int fr = 0; fr < 2; ++fr)
#pragma unroll
    for (int fc = 0; fc < 2; ++fc) {
      // accT: lane = row rr, cols cb..cb+3 (row-major)
      int rr = r0 + (fr << 4) + la;
      int cb = c0 + (fc << 4) + (g << 2);
      float v[4];
#pragma unroll
      for (int j = 0; j < 4; ++j) v[j] = accT[fr][fc][j];
      if constexpr (MK == 2) {
#pragma unroll
        for (int j = 0; j < 4; ++j)
          v[j] = c3 * (v[j] + bf2f(gU[rr * 128 + cb + j]) +
                       bf2f(gU[GPL + rr * 128 + cb + j])) -
                 ((rr == cb + j) ? 1.f : 0.f);
      }
      u16x4 hi, lo;
      pack4(v, hi, lo);
      *(u16x4*)(Mb + MIDX(rr, cb)) = hi;
      *(u16x4*)(Mb + PL + MIDX(rr, cb)) = lo;
      if constexpr (DMP == 1) {
        *(u16x4*)(gd + rr * 128 + cb) = hi;
        *(u16x4*)(gd + GPL + rr * 128 + cb) = lo;
      }
      if constexpr (DMP == 2) {
        cohst8(gd + rr * 128 + cb, hi);
        cohst8(gd + GPL + rr * 128 + cb, lo);
      }
      // acc: lane = col cc, rows rb..rb+3 (col-major)
      int cc = c0 + (fc << 4) + la;
      int rb = r0 + (fr << 4) + (g << 2);
      float q[4];
#pragma unroll
      for (int j = 0; j < 4; ++j) q[j] = acc[fr][fc][j];
      if constexpr (MK == 2) {
#pragma unroll
        for (int j = 0; j < 4; ++j)
          q[j] = c3 * (q[j] + bf2f(gU[(rb + j) * 128 + cc]) +
                       bf2f(gU[GPL + (rb + j) * 128 + cc])) -
                 ((rb + j == cc) ? 1.f : 0.f);
      }
      u16x4 hi2, lo2;
      pack4(q, hi2, lo2);
      *(u16x4*)(Tb + MIDX(cc, rb)) = hi2;
      *(u16x4*)(Tb + PL + MIDX(cc, rb)) = lo2;
      if constexpr (DMP == 3) {
        cohst8(gd + cc * 128 + rb, hi2);
        cohst8(gd + GPL + cc * 128 + rb, lo2);
      }
    }
  if constexpr (ERS > 0) {
#pragma unroll
    for (int f = 0; f < ERS; ++f) {
      int er = (wr << 4) + (f << 6) + la;
#pragma unroll
      for (int fc = 0; fc < 2; ++fc) {
        int cb = c0 + (fc << 4) + (g << 2);
        float v[4];
#pragma unroll
        for (int j = 0; j < 4; ++j) v[j] = accE[f][fc][j];
        if constexpr (M2) {
          u16x4 t1h = *(const u16x4*)(gT1 + er * 128 + cb);
          u16x4 t1l = *(const u16x4*)(gT1 + GPL + er * 128 + cb);
          u16x4 t2h = *(const u16x4*)(gT2x + er * 128 + cb);
          u16x4 t2l = *(const u16x4*)(gT2x + GPL + er * 128 + cb);
#pragma unroll
          for (int j = 0; j < 4; ++j)
            v[j] += bf2f(t1h[j]) + bf2f(t1l[j]) + bf2f(t2h[j]) + bf2f(t2l[j]) +
                    ((er == cb + j) ? 1.f : 0.f);
        }
        u16x4 hi, lo;
        pack4(v, hi, lo);
        *(u16x4*)(gOe + er * 128 + cb) = hi;
        *(u16x4*)(gOe + GPL + er * 128 + cb) = lo;
      }
    }
  }
}

// ---------------------------------------------------------------------------
// Consumer: R-doubling. rt rows = R^T (256x128, lo plane +32768).
// rt[EC+ec] = pw(k) * R[:,ec], ec<EC. A = pw(k) rows (coherent slot).
// ---------------------------------------------------------------------------
__device__ void cons_rdbl(const u16* slot, u16* rt, int EC) {
  const int t = threadIdx.x, lane = t & 63, la = lane & 15, g = lane >> 4;
  const int w = t >> 6, wr = w >> 2, wc = w & 3;
  const int r0 = wr << 5;
  __syncthreads();  // prior rt writes ordered

  f32x4 accC[2][2];
#pragma unroll
  for (int i = 0; i < 2; ++i)
#pragma unroll
    for (int j = 0; j < 2; ++j) accC[i][j] = (f32x4){0.f, 0.f, 0.f, 0.f};

#pragma unroll
  for (int kb = 0; kb < 4; ++kb) {
    const int kp = (kb << 5) + (g << 3);
    bf16x8 Ah[2], Al[2], Fh[2], Fl[2];
#pragma unroll
    for (int fr = 0; fr < 2; ++fr) {
      int ar = r0 + (fr << 4) + la;
      gfragC(slot, ar, kp, Ah[fr], Al[fr]);
    }
#pragma unroll
    for (int e = 0; e < 2; ++e) {
      int ec = (wc << 5) + (e << 4) + la;
      gfragP(rt, 32768, ec, kp, Fh[e], Fl[e]);  // garbage beyond EC is masked
    }
#pragma unroll
    for (int fr = 0; fr < 2; ++fr)
#pragma unroll
      for (int e = 0; e < 2; ++e) {
        accC[fr][e] = MF(Ah[fr], Fh[e], accC[fr][e]);
        accC[fr][e] = MF(Ah[fr], Fl[e], accC[fr][e]);
        accC[fr][e] = MF(Al[fr], Fh[e], accC[fr][e]);
      }
  }
#pragma unroll
  for (int e = 0; e < 2; ++e) {
    int ec = ((t >> 6) & 3) * 32 + (e << 4) + la;
    if (ec < EC) {
#pragma unroll
      for (int fr = 0; fr < 2; ++fr) {
        int rb = r0 + (fr << 4) + (g << 2);
        float v[4];
#pragma unroll
        for (int j = 0; j < 4; ++j) v[j] = accC[fr][e][j];
        u16x4 hi, lo;
        pack4(v, hi, lo);
        *(u16x4*)(rt + (EC + ec) * 128 + rb) = hi;
        *(u16x4*)(rt + 32768 + (EC + ec) * 128 + rb) = lo;
      }
    }
  }
  __syncthreads();  // writes drained before next step's reads
}

// ---------------------------------------------------------------------------
// Consumer: S-doubling. gs rows = S (128x128, lo plane +GPL).
// gs[ER+er] = gs[er] * pw(8+j), er<ER. B = pw^T rows (coherent slotT).
// ---------------------------------------------------------------------------
__device__ void cons_sdbl(const u16* slotT, u16* gs, int ER) {
  const int t = threadIdx.x, lane = t & 63, la = lane & 15, g = lane >> 4;
  const int w = t >> 6, wr = w >> 2, wc = w & 3;
  const int c0 = wc << 5;
  const int er = (wr << 4) + la;  // 0..63
  __syncthreads();

  f32x4 accE[2];
#pragma unroll
  for (int j = 0; j < 2; ++j) accE[j] = (f32x4){0.f, 0.f, 0.f, 0.f};

#pragma unroll
  for (int kb = 0; kb < 4; ++kb) {
    const int kp = (kb << 5) + (g << 3);
    bf16x8 Eh, El, Bh[2], Bl[2];
    gfragP(gs, GPL, er, kp, Eh, El);  // garbage beyond ER masked
#pragma unroll
    for (int fc = 0; fc < 2; ++fc) {
      int bc = c0 + (fc << 4) + la;
      gfragC(slotT, bc, kp, Bh[fc], Bl[fc]);
    }
#pragma unroll
    for (int fc = 0; fc < 2; ++fc) {
      accE[fc] = MF(Bh[fc], Eh, accE[fc]);
      accE[fc] = MF(Bh[fc], El, accE[fc]);
      accE[fc] = MF(Bl[fc], Eh, accE[fc]);
    }
  }
  if (er < ER) {
#pragma unroll
    for (int fc = 0; fc < 2; ++fc) {
      int cb = c0 + (fc << 4) + (g << 2);
      float v[4];
#pragma unroll
      for (int j = 0; j < 4; ++j) v[j] = accE[fc][j];
      u16x4 hi, lo;
      pack4(v, hi, lo);
      *(u16x4*)(gs + (ER + er) * 128 + cb) = hi;
      *(u16x4*)(gs + GPL + (ER + er) * 128 + cb) = lo;
    }
  }
  __syncthreads();
}

// ---------------------------------------------------------------------------
// Chain: 3 blocks. block1 = producer (Neumann + 14 pure-LDS squarings,
// publishing pw(k): rows for k<=7, cols^T for k>=8). block0 = R consumer
// (seed bb + 8 R-dbl). block2 = S consumer (seed C + 7 S-dbl).
// ---------------------------------------------------------------------------
__global__ void __launch_bounds__(1024) chain_k(const float* __restrict__ A,
                                                const float* __restrict__ Bv,
                                                const float* __restrict__ Cv,
                                                const float* __restrict__ lstep,
                                                u16* ws) {
  extern __shared__ u16 lds[];
  int* flags = (int*)ws;                 // [0,1024) bytes
  u16* rt = ws + 512;                    // 65536 u16 (hi, lo at +32768)
  u16* gs = rt + 65536;                  // 32768 u16 (hi, lo at +GPL)
  u16* scr = ws + 512 + 65536 + 32768 + 65536;  // after Kv (65536 u16)
  u16* gT = scr;                         // each 32768 u16 (hi, lo at +GPL)
  u16* gT2 = scr + 32768;
  u16* gU = scr + 65536;
  u16* slots = scr + 98304;              // 15 x 32768 u16

  const int t = threadIdx.x;
  const float stp = expf(lstep[0]);
  const float alpha = 0.5f * stp / (1.f + stp);
  const float c3 = 2.f / (1.f + stp);

  if (blockIdx.x == 1) {
    // ---------------- producer ----------------
    u16* Mh = lds; u16* Ml = lds + PL; u16* Th = lds + 2 * PL; u16* Tl = lds + 3 * PL;
    // s0: T = alpha*(A+2I) -> LDS M+Bt (swizzled) + gT rows (private)
#pragma unroll
    for (int i = 0; i < 4; ++i) {
      int e4 = (t + (i << 10)) << 2;
      int r = e4 >> 7, c = e4 & 127;
      float4 av = *(const float4*)(A + e4);
      float vv[4] = {av.x, av.y, av.z, av.w};
      float tv[4];
#pragma unroll
      for (int j = 0; j < 4; ++j) tv[j] = alpha * (vv[j] + ((r == c + j) ? 2.f : 0.f));
      u16x4 hi, lo;
      pack4(tv, hi, lo);
      *(u16x4*)(Mh + MIDX(r, c)) = hi;
      *(u16x4*)(Ml + MIDX(r, c)) = lo;
      *(u16x4*)(gT + r * 128 + c) = hi;
      *(u16x4*)(gT + GPL + r * 128 + c) = lo;
#pragma unroll
      for (int j = 0; j < 4; ++j) {
        Th[MIDX(c + j, r)] = hi[j];
        Tl[MIDX(c + j, r)] = lo[j];
      }
    }
    // s1: T2 (in-place) + plain dump rows -> gT2
    prod_step<1, 1, 0, false>(lds, 0, 0, 0.f, gT2, 0, 0, 0, 0);
    // s2: T4 (in-place) || U12 = T*T2 + T + T2 + I -> gU (plain)
    prod_step<1, 0, 2, true>(lds, 0, 0, 0.f, 0, gT, gU, gT, gT2);
    // s3: ab = c3*(U12*T4 + U12) - I (A = gU rows) + publish slot0 rows
    prod_step<2, 2, 0, false>(lds, gU, gU, c3, slots + 0, 0, 0, 0, 0);
    setflag(flags + 0);
    // k=1..7: sq + publish rows
    for (int k = 1; k <= 7; ++k) {
      prod_step<1, 2, 0, false>(lds, 0, 0, 0.f, slots + k * 32768, 0, 0, 0, 0);
      setflag(flags + k);
    }
    // k=8..14: sq + publish cols^T
    for (int k = 8; k <= 14; ++k) {
      prod_step<1, 3, 0, false>(lds, 0, 0, 0.f, slots + k * 32768, 0, 0, 0, 0);
      setflag(flags + k);
    }
  } else if (blockIdx.x == 0) {
    // ---------------- R consumer ----------------
    waitflag(flags + 0);
    if (t < 128) {  // seed bb = (stp/2)*(ab*B + B) -> rt row 0
      float a2 = 0.f;
      const u16* s0 = slots;
#pragma unroll 4
      for (int p = 0; p < 128; p += 8) {
        bf16x8 h = cohld16(s0 + t * 128 + p);
        bf16x8 l = cohld16(s0 + GPL + t * 128 + p);
#pragma unroll
        for (int j = 0; j < 8; ++j)
          a2 = fmaf(bf2f((u16)h[j]) + bf2f((u16)l[j]), Bv[p + j], a2);
      }
      float v = 0.5f * stp * (a2 + Bv[t]);
      u16 h = f2bf(v);
      rt[t] = h;
      rt[32768 + t] = f2bf(v - bf2f(h));
    }
    for (int k = 0; k <= 7; ++k) {
      if (k > 0) waitflag(flags + k);
      cons_rdbl(slots + k * 32768, rt, 1 << k);
    }
  } else {
    // ---------------- S consumer ----------------
    if (t < 128) {  // seed S row 0 = C
      float v = Cv[t];
      u16 h = f2bf(v);
      gs[t] = h;
      gs[GPL + t] = f2bf(v - bf2f(h));
    }
    for (int j = 0; j <= 6; ++j) {
      waitflag(flags + 8 + j);
      cons_sdbl(slots + (8 + j) * 32768, gs, 1 << j);
    }
  }
}

// ---------------------------------------------------------------------------
// K[t1*256 + t0] = S[t1] . R[:,t0]
// ---------------------------------------------------------------------------
__global__ __launch_bounds__(256) void kmat_k(const u16* __restrict__ gs,
                                              const u16* __restrict__ rt,
                                              float* __restrict__ Kv) {
  __shared__ float srow[128];
  int t1 = blockIdx.x, t0 = threadIdx.x;
  if (t0 < 128)
    srow[t0] = bf2f(gs[t1 * 128 + t0]) + bf2f(gs[GPL + t1 * 128 + t0]);
  __syncthreads();
  const u16* rh = rt + t0 * 128;
  const u16* rl = rt + 32768 + t0 * 128;
  float acc = 0.f;
#pragma unroll 4
  for (int p = 0; p < 128; p += 8) {
    uint4 qh = *(const uint4*)(rh + p);
    uint4 ql = *(const uint4*)(rl + p);
    unsigned dh[4] = {qh.x, qh.y, qh.z, qh.w};
    unsigned dl[4] = {ql.x, ql.y, ql.z, ql.w};
#pragma unroll
    for (int j = 0; j < 4; ++j) {
      acc = fmaf(srow[p + 2 * j],     bf2f((u16)dh[j]) + bf2f((u16)dl[j]), acc);
      acc = fmaf(srow[p + 2 * j + 1],
                 bf2f((u16)(dh[j] >> 16)) + bf2f((u16)(dl[j] >> 16)), acc);
    }
  }
  Kv[t1 * 256 + t0] = acc;
}

// ---------------------------------------------------------------------------
// Conv partials (r9/r10 proven): task (m, j), m<32, j<2(m+1); 1056 blocks x
// 64 thr, 16 outputs/thread, XOR-swizzled LDS window.
// ---------------------------------------------------------------------------
__global__ __launch_bounds__(64) void conv_k(const float* __restrict__ u,
                                             const float* __restrict__ Kv,
                                             float* __restrict__ Pp) {
  __shared__ __align__(16) float ks[512];
  __shared__ __align__(16) float usw[1536];

  int bid = blockIdx.x, tid = threadIdx.x;
  int m = (int)((sqrtf(4.f * (float)bid + 1.f) - 1.f) * 0.5f);
  while ((m + 1) * (m + 2) <= bid) ++m;
  while (m * (m + 1) > bid) --m;
  int j = bid - m * (m + 1);
  int w0 = (m << 10) - (j << 9) - 512;

  for (int idx = tid; idx < 512; idx += 64) ks[idx] = Kv[(j << 9) + idx];
  for (int idx = tid; idx < 1536; idx += 64) {
    int gi = w0 + idx;
    float v = (gi >= 0) ? u[gi] : 0.f;
    int b = idx >> 2, pb = b ^ ((b >> 3) & 7);
    usw[(pb << 2) | (idx & 3)] = v;
  }
  __syncthreads();

  int tb = tid << 4;
  float acc[16];
#pragma unroll
  for (int z = 0; z < 16; ++z) acc[z] = 0.f;

#define LD4(x) (*(const float4*)&usw[((((x) >> 2) ^ ((((x) >> 2) >> 3) & 7)) << 2)])
  float wf[20];
  {
    float4 a0 = LD4(508 + tb), a1 = LD4(512 + tb), a2 = LD4(516 + tb),
           a3 = LD4(520 + tb), a4 = LD4(524 + tb);
    wf[0] = a0.x; wf[1] = a0.y; wf[2] = a0.z; wf[3] = a0.w;
    wf[4] = a1.x; wf[5] = a1.y; wf[6] = a1.z; wf[7] = a1.w;
    wf[8] = a2.x; wf[9] = a2.y; wf[10] = a2.z; wf[11] = a2.w;
    wf[12] = a3.x; wf[13] = a3.y; wf[14] = a3.z; wf[15] = a3.w;
    wf[16] = a4.x; wf[17] = a4.y; wf[18] = a4.z; wf[19] = a4.w;
  }
  for (int q = 0; q < 512; q += 4) {
    float4 k4 = *(const float4*)&ks[q];
    float kk[4] = {k4.x, k4.y, k4.z, k4.w};
#pragma unroll
    for (int ds = 0; ds < 4; ++ds)
#pragma unroll
      for (int oi = 0; oi < 16; ++oi)
        acc[oi] = fmaf(kk[ds], wf[oi - ds + 4], acc[oi]);
    if (q < 508) {
#pragma unroll
      for (int z = 19; z >= 4; --z) wf[z] = wf[z - 4];
      float4 nw = LD4(504 + tb - q);
      wf[0] = nw.x; wf[1] = nw.y; wf[2] = nw.z; wf[3] = nw.w;
    }
  }
#undef LD4

  float* dst = Pp + (bid << 10) + tb;
#pragma unroll
  for (int z = 0; z < 16; z += 4)
    *(float4*)(dst + z) = make_float4(acc[z], acc[z + 1], acc[z + 2], acc[z + 3]);
}

// ---------------------------------------------------------------------------
// reduce: y[t] = D*u[t] + sum_{j<2(m+1)} Pp[(m(m+1)+j)*1024 + (t&1023)]
// ---------------------------------------------------------------------------
__global__ __launch_bounds__(256) void reduce_k(const float* __restrict__ Pp,
                                                const float* __restrict__ u,
                                                const float* __restrict__ D,
                                                float* __restrict__ y) {
  int t = blockIdx.x * 256 + threadIdx.x;
  if (t >= L_SEQ) return;
  int m = t >> 10;
  int nJ = 2 * (m + 1);
  const float* base = Pp + ((m * (m + 1)) << 10) + (t & 1023);
  float acc = D[0] * u[t];
  for (int j = 0; j < nJ; ++j) acc += base[j << 10];
  y[t] = acc;
}

// ---------------------------------------------------------------------------
// host. ws layout (u16 offsets):
//   flags [0,512) | rt [512,66048) | gs [66048,98816) | Kv f32 [98816,164352)
//   scratch+slots [164352,754176)  (producer scratch 98304 + 15x32768 slots)
//   Pp f32 at byte 328704 (overlaps scratch+slots region; conv runs after
//   chain, kmat only reads rt/gs/Kv) -> ends byte 4654080 < proven extent.
// ---------------------------------------------------------------------------
extern "C" void kernel_launch(void* const* d_in, const int* in_sizes, int n_in,
                              void* d_out, int out_size, void* d_ws, size_t ws_size,
                              hipStream_t stream) {
  (void)in_sizes; (void)n_in; (void)out_size; (void)ws_size;
  const float* u     = (const float*)d_in[0];
  const float* A     = (const float*)d_in[1];
  const float* B     = (const float*)d_in[2];
  const float* C     = (const float*)d_in[3];
  const float* D     = (const float*)d_in[4];
  const float* lstep = (const float*)d_in[5];
  float* y = (float*)d_out;
  u16* ws = (u16*)d_ws;

  u16* rt = ws + 512;
  u16* gs = ws + 66048;
  float* Kv = (float*)((char*)d_ws + 197632);
  float* Pp = (float*)((char*)d_ws + 328704);

  hipMemsetAsync(d_ws, 0, 1024, stream);  // zero flags
  (void)hipFuncSetAttribute((const void*)chain_k,
                            hipFuncAttributeMaxDynamicSharedMemorySize, 131072);
  hipLaunchKernelGGL(chain_k, dim3(3), dim3(1024), 131072, stream, A, B, C, lstep, ws);
  hipLaunchKernelGGL(kmat_k, dim3(128), dim3(256), 0, stream, gs, rt, Kv);
  hipLaunchKernelGGL(conv_k, dim3(1056), dim3(64), 0, stream, u, Kv, Pp);
  hipLaunchKernelGGL(reduce_k, dim3(L_SEQ / 256), dim3(256), 0, stream, Pp, u, D, y);
}